// Round 1
// baseline (1254.965 us; speedup 1.0000x reference)
//
#include <hip/hip_runtime.h>

// Accumulator layout in d_ws (SoA, each array n_frag floats):
//  0: count
//  1..3: sum f (x,y,z)
//  4..6: sum torque (x,y,z)
//  7..12: sum r r^T upper triangle: xx, yy, zz, xy, xz, yz
#define NACC 13

__global__ void atom_accum_kernel(const float* __restrict__ f_atom,
                                  const float* __restrict__ atom_pos,
                                  const float* __restrict__ T_frag,
                                  const int*   __restrict__ frag_id,
                                  float* __restrict__ acc,
                                  int n_atom, int n_frag) {
    int i = blockIdx.x * blockDim.x + threadIdx.x;
    if (i >= n_atom) return;

    float fx = f_atom[3 * i + 0];
    float fy = f_atom[3 * i + 1];
    float fz = f_atom[3 * i + 2];
    float px = atom_pos[3 * i + 0];
    float py = atom_pos[3 * i + 1];
    float pz = atom_pos[3 * i + 2];
    int fid = frag_id[i];

    float rx = px - T_frag[3 * fid + 0];
    float ry = py - T_frag[3 * fid + 1];
    float rz = pz - T_frag[3 * fid + 2];

    // torque = r x f
    float tx = ry * fz - rz * fy;
    float ty = rz * fx - rx * fz;
    float tz = rx * fy - ry * fx;

    atomicAdd(&acc[0 * n_frag + fid], 1.0f);
    atomicAdd(&acc[1 * n_frag + fid], fx);
    atomicAdd(&acc[2 * n_frag + fid], fy);
    atomicAdd(&acc[3 * n_frag + fid], fz);
    atomicAdd(&acc[4 * n_frag + fid], tx);
    atomicAdd(&acc[5 * n_frag + fid], ty);
    atomicAdd(&acc[6 * n_frag + fid], tz);
    atomicAdd(&acc[7 * n_frag + fid], rx * rx);
    atomicAdd(&acc[8 * n_frag + fid], ry * ry);
    atomicAdd(&acc[9 * n_frag + fid], rz * rz);
    atomicAdd(&acc[10 * n_frag + fid], rx * ry);
    atomicAdd(&acc[11 * n_frag + fid], rx * rz);
    atomicAdd(&acc[12 * n_frag + fid], ry * rz);
}

__global__ void finalize_kernel(const float* __restrict__ acc,
                                const int* __restrict__ frag_sizes,
                                float* __restrict__ out,
                                int n_frag) {
    int i = blockIdx.x * blockDim.x + threadIdx.x;
    if (i >= n_frag) return;

    float cnt = acc[0 * n_frag + i];
    float sfx = acc[1 * n_frag + i];
    float sfy = acc[2 * n_frag + i];
    float sfz = acc[3 * n_frag + i];
    float ttx = acc[4 * n_frag + i];
    float tty = acc[5 * n_frag + i];
    float ttz = acc[6 * n_frag + i];
    double sxx = (double)acc[7 * n_frag + i];
    double syy = (double)acc[8 * n_frag + i];
    double szz = (double)acc[9 * n_frag + i];
    double sxy = (double)acc[10 * n_frag + i];
    double sxz = (double)acc[11 * n_frag + i];
    double syz = (double)acc[12 * n_frag + i];

    // v = sum_f / max(count, 1)
    float inv_cnt = 1.0f / fmaxf(cnt, 1.0f);
    out[3 * i + 0] = sfx * inv_cnt;
    out[3 * i + 1] = sfy * inv_cnt;
    out[3 * i + 2] = sfz * inv_cnt;

    // I = (sxx+syy+szz) * eye - S + eps*eye   (S = sum r r^T)
    const double eps = 1e-4;
    double d = sxx + syy + szz;
    double a00 = d - sxx + eps;
    double a11 = d - syy + eps;
    double a22 = d - szz + eps;
    double a01 = -sxy;
    double a02 = -sxz;
    double a12 = -syz;

    // Cramer's rule (symmetric 3x3), in double for stability near eps-scale
    // eigenvalues on single-atom fragments.
    double c00 = a11 * a22 - a12 * a12;
    double c01 = a02 * a12 - a01 * a22;
    double c02 = a01 * a12 - a02 * a11;
    double det = a00 * c00 + a01 * c01 + a02 * c02;
    double inv_det = (det != 0.0) ? 1.0 / det : 0.0;

    double c11 = a00 * a22 - a02 * a02;
    double c12 = a01 * a02 - a00 * a12;
    double c22 = a00 * a11 - a01 * a01;

    double tx = (double)ttx, ty = (double)tty, tz = (double)ttz;
    double ox = (c00 * tx + c01 * ty + c02 * tz) * inv_det;
    double oy = (c01 * tx + c11 * ty + c12 * tz) * inv_det;
    double oz = (c02 * tx + c12 * ty + c22 * tz) * inv_det;

    int fs = frag_sizes[i];
    float* om = out + 3 * (size_t)n_frag;
    if (fs <= 1) {
        om[3 * i + 0] = 0.0f;
        om[3 * i + 1] = 0.0f;
        om[3 * i + 2] = 0.0f;
    } else {
        om[3 * i + 0] = (float)ox;
        om[3 * i + 1] = (float)oy;
        om[3 * i + 2] = (float)oz;
    }
}

extern "C" void kernel_launch(void* const* d_in, const int* in_sizes, int n_in,
                              void* d_out, int out_size, void* d_ws, size_t ws_size,
                              hipStream_t stream) {
    const float* f_atom   = (const float*)d_in[0];
    const float* atom_pos = (const float*)d_in[1];
    const float* T_frag   = (const float*)d_in[2];
    const int*   frag_id  = (const int*)d_in[3];
    // d_in[4] is the n_frag scalar on device; derive on host from T_frag size.
    const int*   frag_sizes = (const int*)d_in[5];

    int n_atom = in_sizes[0] / 3;
    int n_frag = in_sizes[2] / 3;

    float* acc = (float*)d_ws;
    size_t acc_bytes = (size_t)NACC * n_frag * sizeof(float);
    hipMemsetAsync(acc, 0, acc_bytes, stream);

    int threads = 256;
    int blocks_a = (n_atom + threads - 1) / threads;
    atom_accum_kernel<<<blocks_a, threads, 0, stream>>>(f_atom, atom_pos, T_frag,
                                                        frag_id, acc, n_atom, n_frag);

    int blocks_f = (n_frag + threads - 1) / threads;
    finalize_kernel<<<blocks_f, threads, 0, stream>>>(acc, frag_sizes, (float*)d_out,
                                                      n_frag);
}